// Round 6
// baseline (46.668 us; speedup 1.0000x reference)
//
#include <hip/hip_runtime.h>
#include <math.h>

#define BB 32
#define LL 512
#define HH 352
#define WW 1216
#define NLINES (BB * LL)          // 16384
#define WAVES_PER_BLOCK 4
#define NBLOCKS (NLINES / WAVES_PER_BLOCK)  // 4096

__device__ __forceinline__ float line_degree(int x0, int y0, int x1, int y1) {
    // Replicates: slopes = |(y1f - y0f) / (x1f - x0f + 1e-6)|
    //             degrees = (arctan(slopes) * 180.0 / pi) % 90.0
    float slope = fabsf(((float)y1 - (float)y0) / ((float)x1 - (float)x0 + 1e-6f));
    float deg = (atanf(slope) * 180.0f) / 3.14159274101257324f;  // f32(pi)
    return fmodf(deg, 90.0f);
}

__global__ void deg_max_kernel(const int* __restrict__ lines, float* __restrict__ mx) {
    __shared__ float red[LL];
    int b = blockIdx.x;
    int t = threadIdx.x;
    int4 ln = ((const int4*)lines)[b * LL + t];
    int x0 = min(max(ln.x, 0), WW - 1);
    int y0 = min(max(ln.y, 0), HH - 1);
    int x1 = min(max(ln.z, 0), WW - 1);
    int y1 = min(max(ln.w, 0), HH - 1);
    red[t] = line_degree(x0, y0, x1, y1);
    __syncthreads();
    for (int s = LL / 2; s > 0; s >>= 1) {
        if (t < s) red[t] = fmaxf(red[t], red[t + s]);
        __syncthreads();
    }
    if (t == 0) mx[b] = red[0];
}

__global__ void __launch_bounds__(256) line_walk_kernel(
        const float* __restrict__ pred, const int* __restrict__ lines,
        const float* __restrict__ mx, float* __restrict__ partials) {
    int lane = threadIdx.x & 63;
    int w = threadIdx.x >> 6;
    // XCD-aware swizzle: each XCD gets a contiguous chunk of lines
    // (4 batches -> 6.8 MB working set per 4 MiB L2 + reuse).
    int bid = blockIdx.x;
    int swz = (bid & 7) * (NBLOCKS / 8) + (bid >> 3);
    int g = swz * WAVES_PER_BLOCK + w;   // global line id
    int b = g >> 9;                      // / LL

    int4 ln = ((const int4*)lines)[g];
    int x0 = min(max(ln.x, 0), WW - 1);
    int y0 = min(max(ln.y, 0), HH - 1);
    int x1 = min(max(ln.z, 0), WW - 1);
    int y1 = min(max(ln.w, 0), HH - 1);

    int dx = abs(x1 - x0), dy = abs(y1 - y0);
    bool xm = dx > dy;
    int dmaj = xm ? dx : dy;
    int dmin = xm ? dy : dx;
    int sx = (x1 > x0) - (x1 < x0);
    int sy = (y1 > y0) - (y1 < y0);
    int smaj = xm ? sx : sy;
    int smin = xm ? sy : sx;
    int maj0 = xm ? x0 : y0;
    int min0 = xm ? y0 : x0;

    const float* __restrict__ p = pred + (size_t)b * (HH * WW);

    float s = 0.0f;
    if (dmaj > 0) {
        unsigned den = 2u * (unsigned)dmaj;
        int tdm = 2 * dmin;
        // Wave-uniform magic reciprocal: q = floor(num/den) exactly for
        // num < 2^22 via q' = umulhi(num, M) in {q, q+1} + 1-step fixup.
        unsigned M = 0xFFFFFFFFu / den + 1u;
        int sA = xm ? 1 : WW;            // major-axis element stride
        int sB = xm ? WW : 1;            // minor-axis element stride
        int A = smaj * sA;
        int Bm = smin * sB;
        int off0 = maj0 * sA + min0 * sB;
        // 63-point chunk advance: chunk j+1's lane 0 reloads chunk j's
        // lane-63 point -> no broadcast shuffle, no cross-iter dependency.
        int niter = (dmaj + 62) / 63;
        int idx = lane;
        #pragma unroll 2
        for (int j = 0; j < niter; ++j, idx += 63) {
            int idc = min(idx, dmaj);    // clamp: padding repeats endpoint
            unsigned num = (unsigned)(tdm * idc) + den / 2u;  // tdm*idc + dmaj
            unsigned q = __umulhi(num, M);
            q -= (q * den > num) ? 1u : 0u;
            int off = off0 + idc * A + (int)q * Bm;
            float v = p[off];
            float vn = __shfl_down(v, 1);
            float d = fabsf(vn - v);     // clamp makes d=0 past the endpoint
            s += (lane < 63) ? d : 0.0f;
        }
    }
    // wave-level sum reduction (64 lanes)
    #pragma unroll
    for (int offr = 32; offr > 0; offr >>= 1) s += __shfl_down(s, offr);

    if (lane == 0) {
        // end_diff mask: vals[0] = pred[y0,x0], vals[-1] = pred[y1,x1]
        float vf = p[y0 * WW + x0];
        float vl = p[y1 * WW + x1];
        if (fabsf(vf - vl) < 0.5f) s = 0.0f;

        float deg = line_degree(x0, y0, x1, y1);
        float mxv = mx[b];
        float skewed = powf(deg, 1.5f) / powf(mxv + 1.0f, 0.5f);
        float t = fabsf(skewed - 45.0f);
        float h = 90.0f - powf(powf(t, 2.5f), 0.4f);
        float wgt = powf(h * (1.0f / 300.0f), 4.0f);
        partials[g] = wgt * s;           // per-wave write, no block barrier
    }
}

__global__ void final_reduce_kernel(const float* __restrict__ partials,
                                    float* __restrict__ out) {
    __shared__ float red[256];
    int t = threadIdx.x;
    float s = 0.0f;
    const float4* p4 = (const float4*)partials;
    for (int i = t; i < NLINES / 4; i += 256) {
        float4 v = p4[i];
        s += v.x + v.y + v.z + v.w;
    }
    red[t] = s;
    __syncthreads();
    for (int k = 128; k > 0; k >>= 1) {
        if (t < k) red[t] += red[t + k];
        __syncthreads();
    }
    if (t == 0) out[0] = red[0];
}

extern "C" void kernel_launch(void* const* d_in, const int* in_sizes, int n_in,
                              void* d_out, int out_size, void* d_ws, size_t ws_size,
                              hipStream_t stream) {
    const float* pred = (const float*)d_in[0];
    const int* lines = (const int*)d_in[1];
    float* out = (float*)d_out;
    float* ws = (float*)d_ws;
    float* mx = ws;                 // 32 floats
    float* partials = ws + 32;      // 16384 floats (16-byte aligned: 32*4)

    deg_max_kernel<<<BB, LL, 0, stream>>>(lines, mx);
    line_walk_kernel<<<NBLOCKS, 256, 0, stream>>>(pred, lines, mx, partials);
    final_reduce_kernel<<<1, 256, 0, stream>>>(partials, out);
}

// Round 7
// 45.481 us; speedup vs baseline: 1.0261x; 1.0261x over previous
//
#include <hip/hip_runtime.h>
#include <math.h>

#define BB 32
#define LL 512
#define HH 352
#define WW 1216
#define NLINES (BB * LL)          // 16384
#define WAVES_PER_BLOCK 4
#define NBLOCKS (NLINES / WAVES_PER_BLOCK)  // 4096

__device__ __forceinline__ float line_degree(int x0, int y0, int x1, int y1) {
    // Replicates: slopes = |(y1f - y0f) / (x1f - x0f + 1e-6)|
    //             degrees = (arctan(slopes) * 180.0 / pi) % 90.0
    float slope = fabsf(((float)y1 - (float)y0) / ((float)x1 - (float)x0 + 1e-6f));
    float deg = (atanf(slope) * 180.0f) / 3.14159274101257324f;  // f32(pi)
    return fmodf(deg, 90.0f);
}

__global__ void deg_max_kernel(const int* __restrict__ lines, float* __restrict__ mx) {
    __shared__ float red[LL];
    int b = blockIdx.x;
    int t = threadIdx.x;
    int4 ln = ((const int4*)lines)[b * LL + t];
    int x0 = min(max(ln.x, 0), WW - 1);
    int y0 = min(max(ln.y, 0), HH - 1);
    int x1 = min(max(ln.z, 0), WW - 1);
    int y1 = min(max(ln.w, 0), HH - 1);
    red[t] = line_degree(x0, y0, x1, y1);
    __syncthreads();
    for (int s = LL / 2; s > 0; s >>= 1) {
        if (t < s) red[t] = fmaxf(red[t], red[t + s]);
        __syncthreads();
    }
    if (t == 0) mx[b] = red[0];
}

__global__ void __launch_bounds__(256) line_walk_kernel(
        const float* __restrict__ pred, const int* __restrict__ lines,
        const float* __restrict__ mx, float* __restrict__ partials) {
    int lane = threadIdx.x & 63;
    int w = threadIdx.x >> 6;
    // XCD-aware swizzle: each XCD gets a contiguous chunk of lines.
    int bid = blockIdx.x;
    int swz = (bid & 7) * (NBLOCKS / 8) + (bid >> 3);
    int g = swz * WAVES_PER_BLOCK + w;   // global line id
    int b = g >> 9;                      // / LL

    int4 ln = ((const int4*)lines)[g];
    int x0 = min(max(ln.x, 0), WW - 1);
    int y0 = min(max(ln.y, 0), HH - 1);
    int x1 = min(max(ln.z, 0), WW - 1);
    int y1 = min(max(ln.w, 0), HH - 1);

    int dx = abs(x1 - x0), dy = abs(y1 - y0);
    bool xm = dx > dy;
    int dmaj = xm ? dx : dy;
    int dmin = xm ? dy : dx;
    int sx = (x1 > x0) - (x1 < x0);
    int sy = (y1 > y0) - (y1 < y0);
    int smaj = xm ? sx : sy;
    int smin = xm ? sy : sx;
    int maj0 = xm ? x0 : y0;
    int min0 = xm ? y0 : x0;

    const float* __restrict__ p = pred + (size_t)b * (HH * WW);

    float s = 0.0f;
    if (dmaj > 0) {
        unsigned den = 2u * (unsigned)dmaj;
        int tdm = 2 * dmin;
        // Wave-uniform magic reciprocal: exact floor(num/den) for num < 2^22.
        unsigned M = 0xFFFFFFFFu / den + 1u;
        int sA = xm ? 1 : WW;            // major-axis element stride
        int sB = xm ? WW : 1;            // minor-axis element stride
        int A = smaj * sA;
        int Bm = smin * sB;
        int off0 = maj0 * sA + min0 * sB;
        // 63-point chunk advance; idc-clamp makes over-run chunks read the
        // endpoint (same-addr broadcast, diff 0) -> branchless 8-deep batches.
        int niter = (dmaj + 62) / 63;
        int nbatch = (niter + 7) >> 3;
        int idx = lane;
        for (int t = 0; t < nbatch; ++t, idx += 504) {
            int offs[8];
            #pragma unroll
            for (int k = 0; k < 8; ++k) {
                int idc = min(idx + 63 * k, dmaj);
                unsigned num = (unsigned)(tdm * idc) + (unsigned)dmaj;
                unsigned q = __umulhi(num, M);
                q -= (q * den > num) ? 1u : 0u;
                offs[k] = off0 + idc * A + (int)q * Bm;
            }
            float v[8];
            #pragma unroll
            for (int k = 0; k < 8; ++k) v[k] = p[offs[k]];   // 8 gathers in flight
            #pragma unroll
            for (int k = 0; k < 8; ++k) {
                float vn = __shfl_down(v[k], 1);
                float d = fabsf(vn - v[k]);
                s += (lane < 63) ? d : 0.0f;
            }
        }
    }
    // wave-level sum reduction (64 lanes)
    #pragma unroll
    for (int offr = 32; offr > 0; offr >>= 1) s += __shfl_down(s, offr);

    if (lane == 0) {
        // end_diff mask: vals[0] = pred[y0,x0], vals[-1] = pred[y1,x1]
        float vf = p[y0 * WW + x0];
        float vl = p[y1 * WW + x1];
        if (fabsf(vf - vl) < 0.5f) s = 0.0f;

        float deg = line_degree(x0, y0, x1, y1);
        float mxv = mx[b];
        float skewed = powf(deg, 1.5f) / powf(mxv + 1.0f, 0.5f);
        float t = fabsf(skewed - 45.0f);
        float h = 90.0f - powf(powf(t, 2.5f), 0.4f);
        float wgt = powf(h * (1.0f / 300.0f), 4.0f);
        partials[g] = wgt * s;           // per-wave write, no block barrier
    }
}

__global__ void final_reduce_kernel(const float* __restrict__ partials,
                                    float* __restrict__ out) {
    __shared__ float red[256];
    int t = threadIdx.x;
    float s = 0.0f;
    const float4* p4 = (const float4*)partials;
    for (int i = t; i < NLINES / 4; i += 256) {
        float4 v = p4[i];
        s += v.x + v.y + v.z + v.w;
    }
    red[t] = s;
    __syncthreads();
    for (int k = 128; k > 0; k >>= 1) {
        if (t < k) red[t] += red[t + k];
        __syncthreads();
    }
    if (t == 0) out[0] = red[0];
}

extern "C" void kernel_launch(void* const* d_in, const int* in_sizes, int n_in,
                              void* d_out, int out_size, void* d_ws, size_t ws_size,
                              hipStream_t stream) {
    const float* pred = (const float*)d_in[0];
    const int* lines = (const int*)d_in[1];
    float* out = (float*)d_out;
    float* ws = (float*)d_ws;
    float* mx = ws;                 // 32 floats
    float* partials = ws + 32;      // 16384 floats (16-byte aligned: 32*4)

    deg_max_kernel<<<BB, LL, 0, stream>>>(lines, mx);
    line_walk_kernel<<<NBLOCKS, 256, 0, stream>>>(pred, lines, mx, partials);
    final_reduce_kernel<<<1, 256, 0, stream>>>(partials, out);
}

// Round 8
// 45.273 us; speedup vs baseline: 1.0308x; 1.0046x over previous
//
#include <hip/hip_runtime.h>
#include <math.h>

#define BB 32
#define LL 512
#define HH 352
#define WW 1216
#define NLINES (BB * LL)          // 16384
#define WAVES_PER_BLOCK 4
#define NBLOCKS (NLINES / WAVES_PER_BLOCK)  // 4096

typedef float f4 __attribute__((ext_vector_type(4), aligned(4)));

__device__ __forceinline__ float line_degree(int x0, int y0, int x1, int y1) {
    // Replicates: slopes = |(y1f - y0f) / (x1f - x0f + 1e-6)|
    //             degrees = (arctan(slopes) * 180.0 / pi) % 90.0
    float slope = fabsf(((float)y1 - (float)y0) / ((float)x1 - (float)x0 + 1e-6f));
    float deg = (atanf(slope) * 180.0f) / 3.14159274101257324f;  // f32(pi)
    return fmodf(deg, 90.0f);
}

__global__ void deg_max_kernel(const int* __restrict__ lines, float* __restrict__ mx) {
    __shared__ float red[LL];
    int b = blockIdx.x;
    int t = threadIdx.x;
    int4 ln = ((const int4*)lines)[b * LL + t];
    int x0 = min(max(ln.x, 0), WW - 1);
    int y0 = min(max(ln.y, 0), HH - 1);
    int x1 = min(max(ln.z, 0), WW - 1);
    int y1 = min(max(ln.w, 0), HH - 1);
    red[t] = line_degree(x0, y0, x1, y1);
    __syncthreads();
    for (int s = LL / 2; s > 0; s >>= 1) {
        if (t < s) red[t] = fmaxf(red[t], red[t + s]);
        __syncthreads();
    }
    if (t == 0) mx[b] = red[0];
}

__global__ void __launch_bounds__(256) line_walk_kernel(
        const float* __restrict__ pred, const int* __restrict__ lines,
        const float* __restrict__ mx, float* __restrict__ partials) {
    int lane = threadIdx.x & 63;
    int w = threadIdx.x >> 6;
    // XCD-aware swizzle: each XCD gets a contiguous chunk of lines.
    int bid = blockIdx.x;
    int swz = (bid & 7) * (NBLOCKS / 8) + (bid >> 3);
    int g = swz * WAVES_PER_BLOCK + w;   // global line id
    int b = g >> 9;                      // / LL

    int4 ln = ((const int4*)lines)[g];
    int x0 = min(max(ln.x, 0), WW - 1);
    int y0 = min(max(ln.y, 0), HH - 1);
    int x1 = min(max(ln.z, 0), WW - 1);
    int y1 = min(max(ln.w, 0), HH - 1);

    int dx = abs(x1 - x0), dy = abs(y1 - y0);
    bool xm = dx > dy;
    int dmaj = xm ? dx : dy;
    int dmin = xm ? dy : dx;

    const float* __restrict__ p = pred + (size_t)b * (HH * WW);

    float s = 0.0f;
    if (dmaj > 0) {
        if (dy == 0) {
            // ---- Horizontal fast path (~51% of lines: both y clipped) ----
            // Path = contiguous floats in one row; sum of |adjacent diffs|
            // is direction-invariant. Vectorize pairs 4-at-a-time.
            int rb = y0 * WW;
            int xlo = min(x0, x1);
            int dxs = dmaj;                  // xhi - xlo
            int PV = dxs & ~3;               // pairs covered by vector part
            int nch = (PV + 255) >> 8;       // 256 pairs per wave-chunk
            for (int j = 0; j < nch; ++j) {
                int p0 = (j << 8) + (lane << 2);
                bool act = p0 < PV;
                int c = rb + xlo + (act ? p0 : 0);
                f4 lo = *(const f4*)(p + c);
                f4 hi = *(const f4*)(p + c + 1);
                if (act) {
                    s += fabsf(hi.x - lo.x) + fabsf(hi.y - lo.y)
                       + fabsf(hi.z - lo.z) + fabsf(hi.w - lo.w);
                }
            }
            if (lane < 3) {                  // <=3 tail pairs
                int i = PV + lane;
                if (i < dxs) {
                    float a  = p[rb + xlo + i];
                    float bv = p[rb + xlo + i + 1];
                    s += fabsf(bv - a);
                }
            }
        } else {
            // ---- General scattered path (sloped / vertical lines) ----
            int sx = (x1 > x0) - (x1 < x0);
            int sy = (y1 > y0) - (y1 < y0);
            int smaj = xm ? sx : sy;
            int smin = xm ? sy : sx;
            int maj0 = xm ? x0 : y0;
            int min0 = xm ? y0 : x0;
            unsigned den = 2u * (unsigned)dmaj;
            int tdm = 2 * dmin;
            // Wave-uniform magic reciprocal: exact floor(num/den), num < 2^22.
            unsigned M = 0xFFFFFFFFu / den + 1u;
            int sA = xm ? 1 : WW;            // major-axis element stride
            int sB = xm ? WW : 1;            // minor-axis element stride
            int A = smaj * sA;
            int Bm = smin * sB;
            int off0 = maj0 * sA + min0 * sB;
            // 63-point chunk advance; idc-clamp makes over-run chunks read the
            // endpoint (same-addr broadcast, diff 0) -> branchless 8-deep batches.
            int niter = (dmaj + 62) / 63;
            int nbatch = (niter + 7) >> 3;
            int idx = lane;
            for (int t = 0; t < nbatch; ++t, idx += 504) {
                int offs[8];
                #pragma unroll
                for (int k = 0; k < 8; ++k) {
                    int idc = min(idx + 63 * k, dmaj);
                    unsigned num = (unsigned)(tdm * idc) + (unsigned)dmaj;
                    unsigned q = __umulhi(num, M);
                    q -= (q * den > num) ? 1u : 0u;
                    offs[k] = off0 + idc * A + (int)q * Bm;
                }
                float v[8];
                #pragma unroll
                for (int k = 0; k < 8; ++k) v[k] = p[offs[k]];
                #pragma unroll
                for (int k = 0; k < 8; ++k) {
                    float vn = __shfl_down(v[k], 1);
                    float d = fabsf(vn - v[k]);
                    s += (lane < 63) ? d : 0.0f;
                }
            }
        }
    }
    // wave-level sum reduction (64 lanes)
    #pragma unroll
    for (int offr = 32; offr > 0; offr >>= 1) s += __shfl_down(s, offr);

    if (lane == 0) {
        // end_diff mask: vals[0] = pred[y0,x0], vals[-1] = pred[y1,x1]
        float vf = p[y0 * WW + x0];
        float vl = p[y1 * WW + x1];
        if (fabsf(vf - vl) < 0.5f) s = 0.0f;

        float deg = line_degree(x0, y0, x1, y1);
        float mxv = mx[b];
        float skewed = powf(deg, 1.5f) / powf(mxv + 1.0f, 0.5f);
        float t = fabsf(skewed - 45.0f);
        float h = 90.0f - powf(powf(t, 2.5f), 0.4f);
        float wgt = powf(h * (1.0f / 300.0f), 4.0f);
        partials[g] = wgt * s;           // per-wave write, no block barrier
    }
}

__global__ void final_reduce_kernel(const float* __restrict__ partials,
                                    float* __restrict__ out) {
    __shared__ float red[256];
    int t = threadIdx.x;
    float s = 0.0f;
    const float4* p4 = (const float4*)partials;
    for (int i = t; i < NLINES / 4; i += 256) {
        float4 v = p4[i];
        s += v.x + v.y + v.z + v.w;
    }
    red[t] = s;
    __syncthreads();
    for (int k = 128; k > 0; k >>= 1) {
        if (t < k) red[t] += red[t + k];
        __syncthreads();
    }
    if (t == 0) out[0] = red[0];
}

extern "C" void kernel_launch(void* const* d_in, const int* in_sizes, int n_in,
                              void* d_out, int out_size, void* d_ws, size_t ws_size,
                              hipStream_t stream) {
    const float* pred = (const float*)d_in[0];
    const int* lines = (const int*)d_in[1];
    float* out = (float*)d_out;
    float* ws = (float*)d_ws;
    float* mx = ws;                 // 32 floats
    float* partials = ws + 32;      // 16384 floats (16-byte aligned: 32*4)

    deg_max_kernel<<<BB, LL, 0, stream>>>(lines, mx);
    line_walk_kernel<<<NBLOCKS, 256, 0, stream>>>(pred, lines, mx, partials);
    final_reduce_kernel<<<1, 256, 0, stream>>>(partials, out);
}

// Round 9
// 29.015 us; speedup vs baseline: 1.6084x; 1.5603x over previous
//
#include <hip/hip_runtime.h>
#include <math.h>

#define BB 32
#define LL 512
#define HH 352
#define WW 1216
#define NLINES (BB * LL)          // 16384
#define WAVES_PER_BLOCK 4
#define NBLOCKS (NLINES / WAVES_PER_BLOCK)  // 4096

typedef float f4 __attribute__((ext_vector_type(4), aligned(4)));

__device__ __forceinline__ float line_degree(int x0, int y0, int x1, int y1) {
    // Replicates: slopes = |(y1f - y0f) / (x1f - x0f + 1e-6)|
    //             degrees = (arctan(slopes) * 180.0 / pi) % 90.0
    float slope = fabsf(((float)y1 - (float)y0) / ((float)x1 - (float)x0 + 1e-6f));
    float deg = (atanf(slope) * 180.0f) / 3.14159274101257324f;  // f32(pi)
    return fmodf(deg, 90.0f);
}

// Per-line prep: degree, per-batch max, then the full transcendental weight —
// computed once per line with ALL lanes active (vs lane0-only in the walk).
__global__ void line_prep_kernel(const int* __restrict__ lines,
                                 float* __restrict__ weights) {
    __shared__ float red[LL];
    int b = blockIdx.x;
    int t = threadIdx.x;
    int4 ln = ((const int4*)lines)[b * LL + t];
    int x0 = min(max(ln.x, 0), WW - 1);
    int y0 = min(max(ln.y, 0), HH - 1);
    int x1 = min(max(ln.z, 0), WW - 1);
    int y1 = min(max(ln.w, 0), HH - 1);
    float deg = line_degree(x0, y0, x1, y1);
    red[t] = deg;
    __syncthreads();
    for (int s = LL / 2; s > 0; s >>= 1) {
        if (t < s) red[t] = fmaxf(red[t], red[t + s]);
        __syncthreads();
    }
    float mxv = red[0];
    // Same ops, same order as the original epilogue -> bitwise-identical.
    float skewed = powf(deg, 1.5f) / powf(mxv + 1.0f, 0.5f);
    float tt = fabsf(skewed - 45.0f);
    float h = 90.0f - powf(powf(tt, 2.5f), 0.4f);
    float wgt = powf(h * (1.0f / 300.0f), 4.0f);
    weights[b * LL + t] = wgt;
}

__global__ void __launch_bounds__(256) line_walk_kernel(
        const float* __restrict__ pred, const int* __restrict__ lines,
        const float* __restrict__ weights, float* __restrict__ partials) {
    int lane = threadIdx.x & 63;
    int w = threadIdx.x >> 6;
    // XCD-aware swizzle: each XCD gets a contiguous chunk of lines.
    int bid = blockIdx.x;
    int swz = (bid & 7) * (NBLOCKS / 8) + (bid >> 3);
    int g = swz * WAVES_PER_BLOCK + w;   // global line id
    int b = g >> 9;                      // / LL

    int4 ln = ((const int4*)lines)[g];
    int x0 = min(max(ln.x, 0), WW - 1);
    int y0 = min(max(ln.y, 0), HH - 1);
    int x1 = min(max(ln.z, 0), WW - 1);
    int y1 = min(max(ln.w, 0), HH - 1);

    int dx = abs(x1 - x0), dy = abs(y1 - y0);
    bool xm = dx > dy;
    int dmaj = xm ? dx : dy;
    int dmin = xm ? dy : dx;

    const float* __restrict__ p = pred + (size_t)b * (HH * WW);

    float s = 0.0f;
    if (dmaj > 0) {
        if (dy == 0) {
            // ---- Horizontal fast path (~51% of lines: both y clipped) ----
            int rb = y0 * WW;
            int xlo = min(x0, x1);
            int dxs = dmaj;                  // xhi - xlo
            int PV = dxs & ~3;               // pairs covered by vector part
            int nch = (PV + 255) >> 8;       // 256 pairs per wave-chunk
            for (int j = 0; j < nch; ++j) {
                int p0 = (j << 8) + (lane << 2);
                bool act = p0 < PV;
                int c = rb + xlo + (act ? p0 : 0);
                f4 lo = *(const f4*)(p + c);
                f4 hi = *(const f4*)(p + c + 1);
                if (act) {
                    s += fabsf(hi.x - lo.x) + fabsf(hi.y - lo.y)
                       + fabsf(hi.z - lo.z) + fabsf(hi.w - lo.w);
                }
            }
            if (lane < 3) {                  // <=3 tail pairs
                int i = PV + lane;
                if (i < dxs) {
                    float a  = p[rb + xlo + i];
                    float bv = p[rb + xlo + i + 1];
                    s += fabsf(bv - a);
                }
            }
        } else {
            // ---- General scattered path (sloped / vertical lines) ----
            int sx = (x1 > x0) - (x1 < x0);
            int sy = (y1 > y0) - (y1 < y0);
            int smaj = xm ? sx : sy;
            int smin = xm ? sy : sx;
            int maj0 = xm ? x0 : y0;
            int min0 = xm ? y0 : x0;
            unsigned den = 2u * (unsigned)dmaj;
            int tdm = 2 * dmin;
            // Wave-uniform magic reciprocal: exact floor(num/den), num < 2^22.
            unsigned M = 0xFFFFFFFFu / den + 1u;
            int sA = xm ? 1 : WW;            // major-axis element stride
            int sB = xm ? WW : 1;            // minor-axis element stride
            int A = smaj * sA;
            int Bm = smin * sB;
            int off0 = maj0 * sA + min0 * sB;
            // 63-point chunk advance; idc-clamp makes over-run chunks read the
            // endpoint (same-addr broadcast, diff 0) -> branchless batches.
            int niter = (dmaj + 62) / 63;
            int nbatch = (niter + 7) >> 3;
            int idx = lane;
            for (int t = 0; t < nbatch; ++t, idx += 504) {
                int offs[8];
                #pragma unroll
                for (int k = 0; k < 8; ++k) {
                    int idc = min(idx + 63 * k, dmaj);
                    unsigned num = (unsigned)(tdm * idc) + (unsigned)dmaj;
                    unsigned q = __umulhi(num, M);
                    q -= (q * den > num) ? 1u : 0u;
                    offs[k] = off0 + idc * A + (int)q * Bm;
                }
                float v[8];
                #pragma unroll
                for (int k = 0; k < 8; ++k) v[k] = p[offs[k]];
                #pragma unroll
                for (int k = 0; k < 8; ++k) {
                    float vn = __shfl_down(v[k], 1);
                    float d = fabsf(vn - v[k]);
                    s += (lane < 63) ? d : 0.0f;
                }
            }
        }
    }
    // wave-level sum reduction (64 lanes)
    #pragma unroll
    for (int offr = 32; offr > 0; offr >>= 1) s += __shfl_down(s, offr);

    if (lane == 0) {
        // end_diff mask: vals[0] = pred[y0,x0], vals[-1] = pred[y1,x1]
        float vf = p[y0 * WW + x0];
        float vl = p[y1 * WW + x1];
        if (fabsf(vf - vl) < 0.5f) s = 0.0f;
        partials[g] = weights[g] * s;    // no transcendentals here anymore
    }
}

__global__ void final_reduce_kernel(const float* __restrict__ partials,
                                    float* __restrict__ out) {
    __shared__ float red[256];
    int t = threadIdx.x;
    float s = 0.0f;
    const float4* p4 = (const float4*)partials;
    for (int i = t; i < NLINES / 4; i += 256) {
        float4 v = p4[i];
        s += v.x + v.y + v.z + v.w;
    }
    red[t] = s;
    __syncthreads();
    for (int k = 128; k > 0; k >>= 1) {
        if (t < k) red[t] += red[t + k];
        __syncthreads();
    }
    if (t == 0) out[0] = red[0];
}

extern "C" void kernel_launch(void* const* d_in, const int* in_sizes, int n_in,
                              void* d_out, int out_size, void* d_ws, size_t ws_size,
                              hipStream_t stream) {
    const float* pred = (const float*)d_in[0];
    const int* lines = (const int*)d_in[1];
    float* out = (float*)d_out;
    float* ws = (float*)d_ws;
    float* weights = ws;            // 16384 floats
    float* partials = ws + NLINES;  // 16384 floats (16B-aligned)

    line_prep_kernel<<<BB, LL, 0, stream>>>(lines, weights);
    line_walk_kernel<<<NBLOCKS, 256, 0, stream>>>(pred, lines, weights, partials);
    final_reduce_kernel<<<1, 256, 0, stream>>>(partials, out);
}

// Round 10
// 27.546 us; speedup vs baseline: 1.6942x; 1.0533x over previous
//
#include <hip/hip_runtime.h>
#include <math.h>

#define BB 32
#define LL 512
#define HH 352
#define WW 1216
#define NLINES (BB * LL)          // 16384
#define WAVES_PER_BLOCK 4
#define NBLOCKS (NLINES / WAVES_PER_BLOCK)  // 4096

typedef float f4 __attribute__((ext_vector_type(4), aligned(4)));

__device__ __forceinline__ float line_degree(int x0, int y0, int x1, int y1) {
    // Replicates: slopes = |(y1f - y0f) / (x1f - x0f + 1e-6)|
    //             degrees = (arctan(slopes) * 180.0 / pi) % 90.0
    // Kept bit-faithful (atanf + fmodf) because of the %90 wraparound at
    // vertical lines (deg computes to 90.000008 -> wraps to ~0).
    float slope = fabsf(((float)y1 - (float)y0) / ((float)x1 - (float)x0 + 1e-6f));
    float deg = (atanf(slope) * 180.0f) / 3.14159274101257324f;  // f32(pi)
    return fmodf(deg, 90.0f);
}

// Per-line prep: degree, per-batch max, then the weight — all lanes active.
// powf chains strength-reduced: d^1.5 = d*sqrt(d); (t^2.5)^0.4 = t;
// x^4 = sq(sq(x)). Deviation vs libm powf ~1e-5 relative (threshold 112).
__global__ void line_prep_kernel(const int* __restrict__ lines,
                                 float* __restrict__ weights) {
    __shared__ float red[LL];
    int b = blockIdx.x;
    int t = threadIdx.x;
    int4 ln = ((const int4*)lines)[b * LL + t];
    int x0 = min(max(ln.x, 0), WW - 1);
    int y0 = min(max(ln.y, 0), HH - 1);
    int x1 = min(max(ln.z, 0), WW - 1);
    int y1 = min(max(ln.w, 0), HH - 1);
    float deg = line_degree(x0, y0, x1, y1);
    red[t] = deg;
    __syncthreads();
    for (int s = LL / 2; s > 0; s >>= 1) {
        if (t < s) red[t] = fmaxf(red[t], red[t + s]);
        __syncthreads();
    }
    float mxv = red[0];
    float skewed = (deg * sqrtf(deg)) / sqrtf(mxv + 1.0f);
    float tt = fabsf(skewed - 45.0f);
    float h = 90.0f - tt;                    // == 90 - (tt^2.5)^0.4
    float hw = h * (1.0f / 300.0f);
    float hw2 = hw * hw;
    weights[b * LL + t] = hw2 * hw2;         // (h/300)^4
}

__global__ void __launch_bounds__(256) line_walk_kernel(
        const float* __restrict__ pred, const int* __restrict__ lines,
        const float* __restrict__ weights, float* __restrict__ partials) {
    int lane = threadIdx.x & 63;
    int w = threadIdx.x >> 6;
    // XCD-aware swizzle: each XCD gets a contiguous chunk of lines.
    int bid = blockIdx.x;
    int swz = (bid & 7) * (NBLOCKS / 8) + (bid >> 3);
    int g = swz * WAVES_PER_BLOCK + w;   // global line id
    int b = g >> 9;                      // / LL

    int4 ln = ((const int4*)lines)[g];
    int x0 = min(max(ln.x, 0), WW - 1);
    int y0 = min(max(ln.y, 0), HH - 1);
    int x1 = min(max(ln.z, 0), WW - 1);
    int y1 = min(max(ln.w, 0), HH - 1);

    int dx = abs(x1 - x0), dy = abs(y1 - y0);
    bool xm = dx > dy;
    int dmaj = xm ? dx : dy;
    int dmin = xm ? dy : dx;

    const float* __restrict__ p = pred + (size_t)b * (HH * WW);

    // Early-out: the reference zeroes diff_sums when |vf - vl| < 0.5
    // (~28% of lines for N(0,1) pred). Wave-uniform -> skip the whole walk.
    float vf = p[y0 * WW + x0];
    float vl = p[y1 * WW + x1];
    bool active = (fabsf(vf - vl) >= 0.5f) && (dmaj > 0);

    float s = 0.0f;
    if (active) {
        if (dy == 0) {
            // ---- Horizontal fast path (~51% of lines: both y clipped) ----
            int rb = y0 * WW;
            int xlo = min(x0, x1);
            int dxs = dmaj;                  // xhi - xlo
            int PV = dxs & ~3;               // pairs covered by vector part
            int nch = (PV + 255) >> 8;       // 256 pairs per wave-chunk
            for (int j = 0; j < nch; ++j) {
                int p0 = (j << 8) + (lane << 2);
                bool act = p0 < PV;
                int c = rb + xlo + (act ? p0 : 0);
                f4 lo = *(const f4*)(p + c);
                f4 hi = *(const f4*)(p + c + 1);
                if (act) {
                    s += fabsf(hi.x - lo.x) + fabsf(hi.y - lo.y)
                       + fabsf(hi.z - lo.z) + fabsf(hi.w - lo.w);
                }
            }
            if (lane < 3) {                  // <=3 tail pairs
                int i = PV + lane;
                if (i < dxs) {
                    float a  = p[rb + xlo + i];
                    float bv = p[rb + xlo + i + 1];
                    s += fabsf(bv - a);
                }
            }
        } else {
            // ---- General scattered path (sloped / vertical lines) ----
            int sx = (x1 > x0) - (x1 < x0);
            int sy = (y1 > y0) - (y1 < y0);
            int smaj = xm ? sx : sy;
            int smin = xm ? sy : sx;
            int maj0 = xm ? x0 : y0;
            int min0 = xm ? y0 : x0;
            unsigned den = 2u * (unsigned)dmaj;
            int tdm = 2 * dmin;
            // Wave-uniform magic reciprocal: exact floor(num/den), num < 2^22.
            unsigned M = 0xFFFFFFFFu / den + 1u;
            int sA = xm ? 1 : WW;            // major-axis element stride
            int sB = xm ? WW : 1;            // minor-axis element stride
            int A = smaj * sA;
            int Bm = smin * sB;
            int off0 = maj0 * sA + min0 * sB;
            // 63-point chunk advance; idc-clamp makes over-run chunks read the
            // endpoint (same-addr broadcast, diff 0) -> branchless batches.
            int niter = (dmaj + 62) / 63;
            int nbatch = (niter + 7) >> 3;
            int idx = lane;
            for (int t = 0; t < nbatch; ++t, idx += 504) {
                int offs[8];
                #pragma unroll
                for (int k = 0; k < 8; ++k) {
                    int idc = min(idx + 63 * k, dmaj);
                    unsigned num = (unsigned)(tdm * idc) + (unsigned)dmaj;
                    unsigned q = __umulhi(num, M);
                    q -= (q * den > num) ? 1u : 0u;
                    offs[k] = off0 + idc * A + (int)q * Bm;
                }
                float v[8];
                #pragma unroll
                for (int k = 0; k < 8; ++k) v[k] = p[offs[k]];
                #pragma unroll
                for (int k = 0; k < 8; ++k) {
                    float vn = __shfl_down(v[k], 1);
                    float d = fabsf(vn - v[k]);
                    s += (lane < 63) ? d : 0.0f;
                }
            }
        }
        // wave-level sum reduction (64 lanes)
        #pragma unroll
        for (int offr = 32; offr > 0; offr >>= 1) s += __shfl_down(s, offr);
    }

    if (lane == 0) {
        partials[g] = active ? weights[g] * s : 0.0f;
    }
}

__global__ void final_reduce_kernel(const float* __restrict__ partials,
                                    float* __restrict__ out) {
    __shared__ float red[256];
    int t = threadIdx.x;
    float s = 0.0f;
    const float4* p4 = (const float4*)partials;
    for (int i = t; i < NLINES / 4; i += 256) {
        float4 v = p4[i];
        s += v.x + v.y + v.z + v.w;
    }
    red[t] = s;
    __syncthreads();
    for (int k = 128; k > 0; k >>= 1) {
        if (t < k) red[t] += red[t + k];
        __syncthreads();
    }
    if (t == 0) out[0] = red[0];
}

extern "C" void kernel_launch(void* const* d_in, const int* in_sizes, int n_in,
                              void* d_out, int out_size, void* d_ws, size_t ws_size,
                              hipStream_t stream) {
    const float* pred = (const float*)d_in[0];
    const int* lines = (const int*)d_in[1];
    float* out = (float*)d_out;
    float* ws = (float*)d_ws;
    float* weights = ws;            // 16384 floats
    float* partials = ws + NLINES;  // 16384 floats (16B-aligned)

    line_prep_kernel<<<BB, LL, 0, stream>>>(lines, weights);
    line_walk_kernel<<<NBLOCKS, 256, 0, stream>>>(pred, lines, weights, partials);
    final_reduce_kernel<<<1, 256, 0, stream>>>(partials, out);
}

// Round 11
// 24.910 us; speedup vs baseline: 1.8735x; 1.1058x over previous
//
#include <hip/hip_runtime.h>
#include <math.h>

#define BB 32
#define LL 512
#define HH 352
#define WW 1216
#define NLINES (BB * LL)          // 16384
#define WAVES_PER_BLOCK 4
#define NBLOCKS (NLINES / WAVES_PER_BLOCK)  // 4096

typedef float f4 __attribute__((ext_vector_type(4), aligned(4)));

__device__ __forceinline__ float line_degree(int x0, int y0, int x1, int y1) {
    // Replicates: slopes = |(y1f - y0f) / (x1f - x0f + 1e-6)|
    //             degrees = (arctan(slopes) * 180.0 / pi) % 90.0
    // Kept bit-faithful (atanf + fmodf) because of the %90 wraparound at
    // vertical lines (deg computes to 90.000008 -> wraps to ~0).
    float slope = fabsf(((float)y1 - (float)y0) / ((float)x1 - (float)x0 + 1e-6f));
    float deg = (atanf(slope) * 180.0f) / 3.14159274101257324f;  // f32(pi)
    return fmodf(deg, 90.0f);
}

// Unweighted diff-sum per line. No dependency on any other kernel.
__global__ void __launch_bounds__(256) line_walk_kernel(
        const float* __restrict__ pred, const int* __restrict__ lines,
        float* __restrict__ partials) {
    int lane = threadIdx.x & 63;
    int w = threadIdx.x >> 6;
    // XCD-aware swizzle: each XCD gets a contiguous chunk of lines.
    int bid = blockIdx.x;
    int swz = (bid & 7) * (NBLOCKS / 8) + (bid >> 3);
    int g = swz * WAVES_PER_BLOCK + w;   // global line id
    int b = g >> 9;                      // / LL

    int4 ln = ((const int4*)lines)[g];
    int x0 = min(max(ln.x, 0), WW - 1);
    int y0 = min(max(ln.y, 0), HH - 1);
    int x1 = min(max(ln.z, 0), WW - 1);
    int y1 = min(max(ln.w, 0), HH - 1);

    int dx = abs(x1 - x0), dy = abs(y1 - y0);
    bool xm = dx > dy;
    int dmaj = xm ? dx : dy;
    int dmin = xm ? dy : dx;

    const float* __restrict__ p = pred + (size_t)b * (HH * WW);

    // Early-out: reference zeroes diff_sums when |vf - vl| < 0.5
    // (~28% of lines for N(0,1) pred). Wave-uniform -> skip the whole walk.
    float vf = p[y0 * WW + x0];
    float vl = p[y1 * WW + x1];
    bool active = (fabsf(vf - vl) >= 0.5f) && (dmaj > 0);

    float s = 0.0f;
    if (active) {
        if (dy == 0) {
            // ---- Horizontal fast path (~51% of lines: both y clipped) ----
            int rb = y0 * WW;
            int xlo = min(x0, x1);
            int dxs = dmaj;                  // xhi - xlo
            int PV = dxs & ~3;               // pairs covered by vector part
            int nch = (PV + 255) >> 8;       // 256 pairs per wave-chunk
            for (int j = 0; j < nch; ++j) {
                int p0 = (j << 8) + (lane << 2);
                bool act = p0 < PV;
                int c = rb + xlo + (act ? p0 : 0);
                f4 lo = *(const f4*)(p + c);
                f4 hi = *(const f4*)(p + c + 1);
                if (act) {
                    s += fabsf(hi.x - lo.x) + fabsf(hi.y - lo.y)
                       + fabsf(hi.z - lo.z) + fabsf(hi.w - lo.w);
                }
            }
            if (lane < 3) {                  // <=3 tail pairs
                int i = PV + lane;
                if (i < dxs) {
                    float a  = p[rb + xlo + i];
                    float bv = p[rb + xlo + i + 1];
                    s += fabsf(bv - a);
                }
            }
        } else {
            // ---- General scattered path (sloped / vertical lines) ----
            int sx = (x1 > x0) - (x1 < x0);
            int sy = (y1 > y0) - (y1 < y0);
            int smaj = xm ? sx : sy;
            int smin = xm ? sy : sx;
            int maj0 = xm ? x0 : y0;
            int min0 = xm ? y0 : x0;
            unsigned den = 2u * (unsigned)dmaj;
            int tdm = 2 * dmin;
            // Wave-uniform magic reciprocal: exact floor(num/den), num < 2^22.
            unsigned M = 0xFFFFFFFFu / den + 1u;
            int sA = xm ? 1 : WW;            // major-axis element stride
            int sB = xm ? WW : 1;            // minor-axis element stride
            int A = smaj * sA;
            int Bm = smin * sB;
            int off0 = maj0 * sA + min0 * sB;
            // 63-point chunk advance; idc-clamp makes over-run chunks read the
            // endpoint (same-addr broadcast, diff 0) -> branchless batches.
            int niter = (dmaj + 62) / 63;
            int nbatch = (niter + 7) >> 3;
            int idx = lane;
            for (int t = 0; t < nbatch; ++t, idx += 504) {
                int offs[8];
                #pragma unroll
                for (int k = 0; k < 8; ++k) {
                    int idc = min(idx + 63 * k, dmaj);
                    unsigned num = (unsigned)(tdm * idc) + (unsigned)dmaj;
                    unsigned q = __umulhi(num, M);
                    q -= (q * den > num) ? 1u : 0u;
                    offs[k] = off0 + idc * A + (int)q * Bm;
                }
                float v[8];
                #pragma unroll
                for (int k = 0; k < 8; ++k) v[k] = p[offs[k]];
                #pragma unroll
                for (int k = 0; k < 8; ++k) {
                    float vn = __shfl_down(v[k], 1);
                    float d = fabsf(vn - v[k]);
                    s += (lane < 63) ? d : 0.0f;
                }
            }
        }
        // wave-level sum reduction (64 lanes)
        #pragma unroll
        for (int offr = 32; offr > 0; offr >>= 1) s += __shfl_down(s, offr);
    }

    if (lane == 0) {
        partials[g] = active ? s : 0.0f;     // unweighted
    }
}

// Degree + per-batch max + weight + weighted block-sum + 1 atomic per block.
// powf chains strength-reduced: d^1.5 = d*sqrt(d); (t^2.5)^0.4 = t;
// x^4 = sq(sq(x)). Deviation vs libm powf ~1e-5 relative (threshold 112).
__global__ void finalize_kernel(const int* __restrict__ lines,
                                const float* __restrict__ partials,
                                float* __restrict__ out) {
    __shared__ float red[LL];
    int b = blockIdx.x;
    int t = threadIdx.x;
    int g = b * LL + t;
    int4 ln = ((const int4*)lines)[g];
    int x0 = min(max(ln.x, 0), WW - 1);
    int y0 = min(max(ln.y, 0), HH - 1);
    int x1 = min(max(ln.z, 0), WW - 1);
    int y1 = min(max(ln.w, 0), HH - 1);
    float deg = line_degree(x0, y0, x1, y1);
    red[t] = deg;
    __syncthreads();
    for (int s = LL / 2; s > 0; s >>= 1) {
        if (t < s) red[t] = fmaxf(red[t], red[t + s]);
        __syncthreads();
    }
    float mxv = red[0];
    __syncthreads();
    float skewed = (deg * sqrtf(deg)) / sqrtf(mxv + 1.0f);
    float tt = fabsf(skewed - 45.0f);
    float h = 90.0f - tt;                    // == 90 - (tt^2.5)^0.4
    float hw = h * (1.0f / 300.0f);
    float hw2 = hw * hw;
    float wgt = hw2 * hw2;                   // (h/300)^4
    red[t] = wgt * partials[g];
    __syncthreads();
    for (int s = LL / 2; s > 0; s >>= 1) {
        if (t < s) red[t] += red[t + s];
        __syncthreads();
    }
    if (t == 0) atomicAdd(out, red[0]);      // 32 atomics total
}

extern "C" void kernel_launch(void* const* d_in, const int* in_sizes, int n_in,
                              void* d_out, int out_size, void* d_ws, size_t ws_size,
                              hipStream_t stream) {
    const float* pred = (const float*)d_in[0];
    const int* lines = (const int*)d_in[1];
    float* out = (float*)d_out;
    float* partials = (float*)d_ws;  // 16384 floats

    hipMemsetAsync(out, 0, sizeof(float), stream);
    line_walk_kernel<<<NBLOCKS, 256, 0, stream>>>(pred, lines, partials);
    finalize_kernel<<<BB, LL, 0, stream>>>(lines, partials, out);
}

// Round 12
// 21.659 us; speedup vs baseline: 2.1547x; 1.1501x over previous
//
#include <hip/hip_runtime.h>
#include <math.h>

#define BB 32
#define LL 512
#define HH 352
#define WW 1216
#define NLINES (BB * LL)          // 16384
#define LPW 2                     // lines per wave
#define NBLK2 (NLINES / (LPW * 4))  // 2048 blocks, 4 waves each

typedef float f4 __attribute__((ext_vector_type(4), aligned(4)));

__device__ __forceinline__ float line_degree(int x0, int y0, int x1, int y1) {
    // Replicates: slopes = |(y1f - y0f) / (x1f - x0f + 1e-6)|
    //             degrees = (arctan(slopes) * 180.0 / pi) % 90.0
    float slope = fabsf(((float)y1 - (float)y0) / ((float)x1 - (float)x0 + 1e-6f));
    float deg = (atanf(slope) * 180.0f) / 3.14159274101257324f;  // f32(pi)
    return fmodf(deg, 90.0f);
}

__device__ __forceinline__ float walk_line(const float* __restrict__ p, int lane,
        int x0, int y0, int x1, int y1, int dy, bool xm, int dmaj, int dmin) {
    float s = 0.0f;
    if (dy == 0) {
        // ---- Horizontal fast path (~51% of lines: both y clipped) ----
        int rb = y0 * WW;
        int xlo = min(x0, x1);
        int dxs = dmaj;                  // xhi - xlo
        int PV = dxs & ~3;               // pairs covered by vector part
        int nch = (PV + 255) >> 8;       // 256 pairs per wave-chunk
        for (int j = 0; j < nch; ++j) {
            int p0 = (j << 8) + (lane << 2);
            bool act = p0 < PV;
            int c = rb + xlo + (act ? p0 : 0);
            f4 lo = *(const f4*)(p + c);
            f4 hi = *(const f4*)(p + c + 1);
            if (act) {
                s += fabsf(hi.x - lo.x) + fabsf(hi.y - lo.y)
                   + fabsf(hi.z - lo.z) + fabsf(hi.w - lo.w);
            }
        }
        if (lane < 3) {                  // <=3 tail pairs
            int i = PV + lane;
            if (i < dxs) {
                float a  = p[rb + xlo + i];
                float bv = p[rb + xlo + i + 1];
                s += fabsf(bv - a);
            }
        }
    } else {
        // ---- General scattered path (sloped / vertical lines) ----
        int sx = (x1 > x0) - (x1 < x0);
        int sy = (y1 > y0) - (y1 < y0);
        int smaj = xm ? sx : sy;
        int smin = xm ? sy : sx;
        int maj0 = xm ? x0 : y0;
        int min0 = xm ? y0 : x0;
        unsigned den = 2u * (unsigned)dmaj;
        int tdm = 2 * dmin;
        // Wave-uniform magic reciprocal: exact floor(num/den), num < 2^22.
        unsigned M = 0xFFFFFFFFu / den + 1u;
        int sA = xm ? 1 : WW;            // major-axis element stride
        int sB = xm ? WW : 1;            // minor-axis element stride
        int A = smaj * sA;
        int Bm = smin * sB;
        int off0 = maj0 * sA + min0 * sB;
        // 63-point chunk advance; idc-clamp makes over-run chunks read the
        // endpoint (same-addr broadcast, diff 0) -> branchless batches.
        int niter = (dmaj + 62) / 63;
        int nbatch = (niter + 7) >> 3;
        int idx = lane;
        for (int t = 0; t < nbatch; ++t, idx += 504) {
            int offs[8];
            #pragma unroll
            for (int k = 0; k < 8; ++k) {
                int idc = min(idx + 63 * k, dmaj);
                unsigned num = (unsigned)(tdm * idc) + (unsigned)dmaj;
                unsigned q = __umulhi(num, M);
                q -= (q * den > num) ? 1u : 0u;
                offs[k] = off0 + idc * A + (int)q * Bm;
            }
            float v[8];
            #pragma unroll
            for (int k = 0; k < 8; ++k) v[k] = p[offs[k]];
            #pragma unroll
            for (int k = 0; k < 8; ++k) {
                float vn = __shfl_down(v[k], 1);
                float d = fabsf(vn - v[k]);
                s += (lane < 63) ? d : 0.0f;
            }
        }
    }
    return s;
}

// Unweighted diff-sums, 2 lines per wave (amortized preamble latency).
__global__ void __launch_bounds__(256) line_walk_kernel(
        const float* __restrict__ pred, const int* __restrict__ lines,
        float* __restrict__ partials, unsigned* __restrict__ counter) {
    if (blockIdx.x == 0 && threadIdx.x == 0) *counter = 0;  // reset for finalize
    int lane = threadIdx.x & 63;
    int w = threadIdx.x >> 6;
    // XCD-aware swizzle: each XCD gets a contiguous chunk of lines.
    int bid = blockIdx.x;
    int swz = (bid & 7) * (NBLK2 / 8) + (bid >> 3);
    int W = swz * 4 + w;                 // wave id
    int g0 = W * LPW, g1 = g0 + 1;
    int b = g0 >> 9;                     // both lines in same batch (LL even)

    int4 lA = ((const int4*)lines)[g0];
    int4 lB = ((const int4*)lines)[g1];
    int ax0 = min(max(lA.x, 0), WW - 1), ay0 = min(max(lA.y, 0), HH - 1);
    int ax1 = min(max(lA.z, 0), WW - 1), ay1 = min(max(lA.w, 0), HH - 1);
    int bx0 = min(max(lB.x, 0), WW - 1), by0 = min(max(lB.y, 0), HH - 1);
    int bx1 = min(max(lB.z, 0), WW - 1), by1 = min(max(lB.w, 0), HH - 1);

    const float* __restrict__ p = pred + (size_t)b * (HH * WW);

    // All 4 endpoint loads issue together (one latency round for both lines).
    float vfA = p[ay0 * WW + ax0];
    float vlA = p[ay1 * WW + ax1];
    float vfB = p[by0 * WW + bx0];
    float vlB = p[by1 * WW + bx1];

    int adx = abs(ax1 - ax0), ady = abs(ay1 - ay0);
    bool axm = adx > ady;
    int admaj = axm ? adx : ady, admin_ = axm ? ady : adx;
    int bdx = abs(bx1 - bx0), bdy = abs(by1 - by0);
    bool bxm = bdx > bdy;
    int bdmaj = bxm ? bdx : bdy, bdmin = bxm ? bdy : bdx;

    // Early-out: reference zeroes diff_sums when |vf - vl| < 0.5.
    bool actA = (fabsf(vfA - vlA) >= 0.5f) && (admaj > 0);
    bool actB = (fabsf(vfB - vlB) >= 0.5f) && (bdmaj > 0);

    float s0 = actA ? walk_line(p, lane, ax0, ay0, ax1, ay1, ady, axm, admaj, admin_) : 0.0f;
    float s1 = actB ? walk_line(p, lane, bx0, by0, bx1, by1, bdy, bxm, bdmaj, bdmin) : 0.0f;

    // Two interleaved wave reductions (dependency chains overlap).
    #pragma unroll
    for (int off = 32; off > 0; off >>= 1) {
        s0 += __shfl_down(s0, off);
        s1 += __shfl_down(s1, off);
    }
    if (lane == 0) {
        partials[g0] = actA ? s0 : 0.0f;
        partials[g1] = actB ? s1 : 0.0f;
    }
}

// Degree + per-batch max + weight + weighted block-sum; last block writes out.
// powf chains strength-reduced: d^1.5 = d*sqrt(d); (t^2.5)^0.4 = t;
// x^4 = sq(sq(x)). Deviation vs libm powf ~1e-5 relative (threshold 112).
__global__ void finalize_kernel(const int* __restrict__ lines,
                                const float* __restrict__ partials,
                                float* __restrict__ bsum,
                                unsigned* __restrict__ counter,
                                float* __restrict__ out) {
    __shared__ float red[LL];
    int b = blockIdx.x;
    int t = threadIdx.x;
    int g = b * LL + t;
    int4 ln = ((const int4*)lines)[g];
    int x0 = min(max(ln.x, 0), WW - 1);
    int y0 = min(max(ln.y, 0), HH - 1);
    int x1 = min(max(ln.z, 0), WW - 1);
    int y1 = min(max(ln.w, 0), HH - 1);
    float deg = line_degree(x0, y0, x1, y1);
    red[t] = deg;
    __syncthreads();
    for (int s = LL / 2; s > 0; s >>= 1) {
        if (t < s) red[t] = fmaxf(red[t], red[t + s]);
        __syncthreads();
    }
    float mxv = red[0];
    __syncthreads();
    float skewed = (deg * sqrtf(deg)) / sqrtf(mxv + 1.0f);
    float tt = fabsf(skewed - 45.0f);
    float h = 90.0f - tt;                    // == 90 - (tt^2.5)^0.4
    float hw = h * (1.0f / 300.0f);
    float hw2 = hw * hw;
    float wgt = hw2 * hw2;                   // (h/300)^4
    red[t] = wgt * partials[g];
    __syncthreads();
    for (int s = LL / 2; s > 0; s >>= 1) {
        if (t < s) red[t] += red[t + s];
        __syncthreads();
    }
    if (t == 0) {
        bsum[b] = red[0];
        __threadfence();                     // release bsum before counter bump
        if (atomicAdd(counter, 1u) == BB - 1) {
            __threadfence();                 // acquire others' bsum
            float tot = 0.0f;
            #pragma unroll
            for (int i = 0; i < BB; ++i) tot += bsum[i];  // fixed order: deterministic
            out[0] = tot;
        }
    }
}

extern "C" void kernel_launch(void* const* d_in, const int* in_sizes, int n_in,
                              void* d_out, int out_size, void* d_ws, size_t ws_size,
                              hipStream_t stream) {
    const float* pred = (const float*)d_in[0];
    const int* lines = (const int*)d_in[1];
    float* out = (float*)d_out;
    float* ws = (float*)d_ws;
    float* partials = ws;                    // 16384 floats
    float* bsum = ws + NLINES;               // 32 floats
    unsigned* counter = (unsigned*)(ws + NLINES + BB);  // 1 uint

    line_walk_kernel<<<NBLK2, 256, 0, stream>>>(pred, lines, partials, counter);
    finalize_kernel<<<BB, LL, 0, stream>>>(lines, partials, bsum, counter, out);
}